// Round 8
// baseline (129.634 us; speedup 1.0000x reference)
//
#include <hip/hip_runtime.h>
#include <hip/hip_fp16.h>

// Per-point expert-indexed MLP: h = LeakyReLU(h @ W[idx] + b[idx]) x3.
//
// R17 = R16 + sentinel-init fix. R16 failed (NaN): spid[512] = 256 ints but
// init wrote ints [t & 127] -> slots 256..511 kept garbage -> pad slots
// passed the 0xFFFF test with garbage expert/local -> OOB weight reads +
// junk stores. Fix: init all 256 ints ([t], t<256). Design unchanged:
//
// R16 theory (untested, not refuted): R15 was latency-bound BY GRID SIZE
// (513 blocks = 2 waves/SIMD; LDS 41984 capped 3 blocks/CU). PPB 976->496
// (2 pts/thread, pad-to-2 groups) -> 1009 blocks ~4/CU; LDS < 40 KiB
// (b1 fp16, spid 512) -> 4 blocks/CU fit -> 16 waves/CU.
// Keep R15 spill containment (sequential pairwise L0, unroll-1 ch loop,
// phase fences; proven 76 VGPR) under launch_bounds(256,4).
//
// L0 bias folded into c=7 pad slot (x7=1.0, w7=b0[o]); b1,b2 staged fp16.

#define L_EXP 16
#define IN0   7
#define C0    16
#define C1    32
#define C2    16
#define NEG   0.2f
#define BLK   256
#define PPB   496         // points per block; padded slots <= 496+16 = 512

typedef _Float16 h2 __attribute__((ext_vector_type(2)));
union F4H { float4 f4; h2 h[4]; };

__device__ __forceinline__ h2 pk(float a, float b) {
    return __builtin_bit_cast(h2, __builtin_amdgcn_cvt_pkrtz(a, b));
}
__device__ __forceinline__ float leaky(float a) { return fmaxf(a, NEG * a); }
__device__ __forceinline__ float fdot2(h2 a, h2 b, float c) {
    return __builtin_amdgcn_fdot2(a, b, c, false);
}

__global__ void __launch_bounds__(BLK, 4) k_fused(
    const float* __restrict__ x, const int* __restrict__ idx,
    const float* __restrict__ W0, const float* __restrict__ b0,
    const float* __restrict__ W1, const float* __restrict__ b1,
    const float* __restrict__ W2, const float* __restrict__ b2,
    float* __restrict__ out, int n) {
    // expert-innermost fp16 weight tiles; 16 B per (row, expert)
    __shared__ __align__(16) __half sW0[C0 * L_EXP * 8];      // [o][e][8]  4 KB
    __shared__ __align__(16) __half sW1[C1 * 2 * L_EXP * 8];  // [o][q2][e][8] 16 KB
    __shared__ __align__(16) __half sW2[C2 * 4 * L_EXP * 8];  // [o][q4][e][8] 16 KB
    __shared__ __half sB1h[C1 * L_EXP];                       // [o][e] 1 KB
    __shared__ __half sB2h[C2 * L_EXP];                       // [o][e] 512 B
    __shared__ unsigned short spid[512];                      // (e<<10)|local, 1 KB
    __shared__ int bins[L_EXP];
    __shared__ int poff[L_EXP];

    int t = threadIdx.x;

    // ---- stage all experts' weights (once per block; proven R13 code) ----
    {   // W0: 256 rows of 8 halves; row k: o=k>>4, e=k&15; c=0..6 + bias slot
        int o = t >> 4, e = t & 15;
        float v0 = W0[e * (IN0 * C0) + 0 * C0 + o];
        float v1 = W0[e * (IN0 * C0) + 1 * C0 + o];
        float v2 = W0[e * (IN0 * C0) + 2 * C0 + o];
        float v3 = W0[e * (IN0 * C0) + 3 * C0 + o];
        float v4 = W0[e * (IN0 * C0) + 4 * C0 + o];
        float v5 = W0[e * (IN0 * C0) + 5 * C0 + o];
        float v6 = W0[e * (IN0 * C0) + 6 * C0 + o];
        float v7 = b0[e * C0 + o];           // bias via x7=1.0
        F4H u;
        u.h[0] = pk(v0, v1); u.h[1] = pk(v2, v3);
        u.h[2] = pk(v4, v5); u.h[3] = pk(v6, v7);
        reinterpret_cast<float4*>(sW0)[t] = u.f4;
    }
#pragma unroll
    for (int rr = 0; rr < 4; ++rr) {  // W1: 1024 rows; row r=(o*2+q2)*16+e
        int r = rr * BLK + t;
        int o = r >> 5, q = (r >> 4) & 1, e = r & 15;
        const float* wp = W1 + e * (C0 * C1) + (q * 8) * C1 + o;
        F4H u;
#pragma unroll
        for (int j = 0; j < 4; ++j)
            u.h[j] = pk(wp[(2 * j) * C1], wp[(2 * j + 1) * C1]);
        reinterpret_cast<float4*>(sW1)[r] = u.f4;
    }
#pragma unroll
    for (int rr = 0; rr < 4; ++rr) {  // W2: 1024 rows; row r=(o*4+q4)*16+e
        int r = rr * BLK + t;
        int o = r >> 6, q = (r >> 4) & 3, e = r & 15;
        const float* wp = W2 + e * (C1 * C2) + (q * 8) * C2 + o;
        F4H u;
#pragma unroll
        for (int j = 0; j < 4; ++j)
            u.h[j] = pk(wp[(2 * j) * C2], wp[(2 * j + 1) * C2]);
        reinterpret_cast<float4*>(sW2)[r] = u.f4;
    }
    {   // biases [o][e] as fp16
        int o = t >> 4, e = t & 15;
        sB1h[t] = __float2half(b1[e * C1 + o]);            // o 0..15
        int r2 = t + 256; int o2 = r2 >> 4, e2 = r2 & 15;
        sB1h[r2] = __float2half(b1[e2 * C1 + o2]);         // o 16..31
        sB2h[t] = __float2half(b2[e * C2 + o]);
    }
    if (t < L_EXP) bins[t] = 0;
    reinterpret_cast<int*>(spid)[t] = -1;   // ALL 256 ints = 512 ushorts (R16 bug fix)
    __syncthreads();

    // ---- block-local sort of up to 496 points, expert groups padded to 2 ----
    int base = blockIdx.x * PPB;
    int cnt = n - base; if (cnt > PPB) cnt = PPB;
    int eL[2], rL[2];
    bool vL[2];
    int i2 = t * 2;   // local ids 2t, 2t+1 (threads 248..255 idle: i2 >= 496)
#pragma unroll
    for (int q = 0; q < 2; ++q) {
        int li = i2 + q;
        vL[q] = (li < cnt);
        if (vL[q]) {
            eL[q] = idx[base + li] & 15;
            rL[q] = atomicAdd(&bins[eL[q]], 1);
        }
    }
    __syncthreads();
    if (t < L_EXP) {   // 16-lane scan of pad2 counts
        int c = bins[t];
        int p = (c + 1) & ~1;
        int s = p;
#pragma unroll
        for (int d = 1; d < L_EXP; d <<= 1) {
            int u = __shfl_up(s, d, L_EXP);
            if (t >= d) s += u;
        }
        poff[t] = s - p;
    }
    __syncthreads();
#pragma unroll
    for (int q = 0; q < 2; ++q)
        if (vL[q]) spid[poff[eL[q]] + rL[q]] =
            (unsigned short)((eL[q] << 10) | (i2 + q));
    __syncthreads();

    // ---- thread processes slots 2t, 2t+1 (same expert by construction:
    //      groups start at even offsets, pads only at odd slot positions) ----
    int s0 = (int)spid[2 * t];
    bool any = (s0 != 0xFFFF);
    int e = any ? (s0 >> 10) : 0;
    int l0 = any ? (s0 & 1023) : 0;
    int pid[2]; bool act[2];
#pragma unroll
    for (int q = 0; q < 2; ++q) {
        int sq = (int)spid[2 * t + q];
        act[q] = (sq != 0xFFFF);
        pid[q] = base + (act[q] ? (sq & 1023) : l0);
    }

    const char* w0p = (const char*)sW0 + e * 16;
    const char* w1p = (const char*)sW1 + e * 16;
    const char* w2p = (const char*)sW2 + e * 16;

    h2 xh[2][4];
#pragma unroll
    for (int q = 0; q < 2; ++q) {
        const float* xp = x + (size_t)pid[q] * IN0;
        float4 a = *reinterpret_cast<const float4*>(xp);
        float4 b = *reinterpret_cast<const float4*>(xp + 3);
        xh[q][0] = pk(a.x, a.y);
        xh[q][1] = pk(a.z, a.w);
        xh[q][2] = pk(b.y, b.z);
        xh[q][3] = pk(b.w, 1.0f);   // 1.0 -> bias slot
    }
    __builtin_amdgcn_sched_barrier(0);

    // ---- Layer 0: 7(+bias) -> 16, pairwise rows, weights shared by 2 pts ----
    h2 h0h[2][8];
#pragma unroll
    for (int op = 0; op < 8; ++op) {
        F4H ua, ub;
        ua.f4 = *reinterpret_cast<const float4*>(w0p + (2 * op) * 256);
        ub.f4 = *reinterpret_cast<const float4*>(w0p + (2 * op + 1) * 256);
#pragma unroll
        for (int q = 0; q < 2; ++q) {
            float a0 = 0.f, a1 = 0.f;
            a0 = fdot2(xh[q][0], ua.h[0], a0); a1 = fdot2(xh[q][0], ub.h[0], a1);
            a0 = fdot2(xh[q][1], ua.h[1], a0); a1 = fdot2(xh[q][1], ub.h[1], a1);
            a0 = fdot2(xh[q][2], ua.h[2], a0); a1 = fdot2(xh[q][2], ub.h[2], a1);
            a0 = fdot2(xh[q][3], ua.h[3], a0); a1 = fdot2(xh[q][3], ub.h[3], a1);
            h0h[q][op] = pk(leaky(a0), leaky(a1));
        }
    }
    __builtin_amdgcn_sched_barrier(0);

    // ---- Layers 1+2 fused; REAL loop over 4 chunks of 8 h1-neurons ----
    float h2a[2][C2];
#pragma unroll
    for (int q = 0; q < 2; ++q)
#pragma unroll
        for (int o = 0; o < C2; ++o)
            h2a[q][o] = __half2float(sB2h[o * 16 + e]);
#pragma unroll 1
    for (int ch = 0; ch < 4; ++ch) {   // h1 neurons ch*8 .. ch*8+7
        float tvf[2][8];
#pragma unroll
        for (int o8 = 0; o8 < 8; ++o8) {
            int o = ch * 8 + o8;
            F4H ua, ub;
            ua.f4 = *reinterpret_cast<const float4*>(w1p + (2 * o) * 256);
            ub.f4 = *reinterpret_cast<const float4*>(w1p + (2 * o + 1) * 256);
            float bias = __half2float(sB1h[o * 16 + e]);
#pragma unroll
            for (int q = 0; q < 2; ++q) {
                float a = bias;
                a = fdot2(h0h[q][0], ua.h[0], a);
                a = fdot2(h0h[q][1], ua.h[1], a);
                a = fdot2(h0h[q][2], ua.h[2], a);
                a = fdot2(h0h[q][3], ua.h[3], a);
                a = fdot2(h0h[q][4], ub.h[0], a);
                a = fdot2(h0h[q][5], ub.h[1], a);
                a = fdot2(h0h[q][6], ub.h[2], a);
                a = fdot2(h0h[q][7], ub.h[3], a);
                tvf[q][o8] = leaky(a);
            }
        }
        __builtin_amdgcn_sched_barrier(0);
        h2 tvh[2][4];
#pragma unroll
        for (int q = 0; q < 2; ++q)
#pragma unroll
            for (int p = 0; p < 4; ++p)
                tvh[q][p] = pk(tvf[q][2 * p], tvf[q][2 * p + 1]);
#pragma unroll
        for (int o = 0; o < C2; ++o) {
            F4H u;
            u.f4 = *reinterpret_cast<const float4*>(w2p + (4 * o + ch) * 256);
#pragma unroll
            for (int q = 0; q < 2; ++q) {
                float a = h2a[q][o];
                a = fdot2(tvh[q][0], u.h[0], a);
                a = fdot2(tvh[q][1], u.h[1], a);
                a = fdot2(tvh[q][2], u.h[2], a);
                a = fdot2(tvh[q][3], u.h[3], a);
                h2a[q][o] = a;
            }
        }
        __builtin_amdgcn_sched_barrier(0);  // fence at chunk boundary
    }

    // ---- predicated stores ----
#pragma unroll
    for (int q = 0; q < 2; ++q) {
        if (act[q]) {
            float4* outp = reinterpret_cast<float4*>(out + (size_t)pid[q] * C2);
#pragma unroll
            for (int og = 0; og < 4; ++og) {
                float4 o;
                o.x = leaky(h2a[q][og * 4 + 0]);
                o.y = leaky(h2a[q][og * 4 + 1]);
                o.z = leaky(h2a[q][og * 4 + 2]);
                o.w = leaky(h2a[q][og * 4 + 3]);
                outp[og] = o;
            }
        }
    }
}

extern "C" void kernel_launch(void* const* d_in, const int* in_sizes, int n_in,
                              void* d_out, int out_size, void* d_ws, size_t ws_size,
                              hipStream_t stream) {
    const float* x  = (const float*)d_in[0];
    const int*  idx = (const int*)d_in[1];
    const float* W0 = (const float*)d_in[2];
    const float* b0 = (const float*)d_in[3];
    const float* W1 = (const float*)d_in[4];
    const float* b1 = (const float*)d_in[5];
    const float* W2 = (const float*)d_in[6];
    const float* b2 = (const float*)d_in[7];
    float* out = (float*)d_out;

    int n = in_sizes[1];  // N
    int blocks = (n + PPB - 1) / PPB;
    k_fused<<<blocks, BLK, 0, stream>>>(x, idx, W0, b0, W1, b1, W2, b2, out, n);
}